// Round 13
// baseline (324.510 us; speedup 1.0000x reference)
//
#include <hip/hip_runtime.h>

// ---------- types ----------
typedef __attribute__((ext_vector_type(8))) __bf16 bf16x8;
typedef __attribute__((ext_vector_type(4))) __bf16 bf16x4;
typedef __attribute__((ext_vector_type(4))) float f32x4;
typedef __attribute__((ext_vector_type(8))) unsigned short u16x8;

// native casts -> v_cvt_pk_bf16_f32 (RNE) on gfx950
__device__ __forceinline__ bf16x8 cvt8(float4 a, float4 b) {
    bf16x8 o;
    o[0] = (__bf16)a.x; o[1] = (__bf16)a.y; o[2] = (__bf16)a.z; o[3] = (__bf16)a.w;
    o[4] = (__bf16)b.x; o[5] = (__bf16)b.y; o[6] = (__bf16)b.z; o[7] = (__bf16)b.w;
    return o;
}
__device__ __forceinline__ bf16x4 cvt4(f32x4 v) {
    bf16x4 o;
    o[0] = (__bf16)v[0]; o[1] = (__bf16)v[1]; o[2] = (__bf16)v[2]; o[3] = (__bf16)v[3];
    return o;
}

// m201 st_16x32 swizzle on 64B rows: flips byte-bit5 with row-bit3.
__device__ __forceinline__ unsigned swz(int row, int s) {
    return (unsigned)((row * 64 + s * 16) ^ ((row & 8) << 2));
}

// ---------- W [K][N=512] f32 -> pre-tiled + pre-swizzled bf16 image ----------
__global__ __launch_bounds__(256) void convw_pre_kernel(const float* __restrict__ W,
                                                        char* __restrict__ out, int K) {
    int t = blockIdx.x * 256 + threadIdx.x;
    if (t >= K * 512) return;
    int k = t >> 9, n = t & 511;
    int cb = n >> 8, r = n & 255, tt = k >> 5, s = (k & 31) >> 3, e = k & 7;
    size_t off = ((size_t)cb * (K >> 5) + tt) * 16384 + swz(r, s) + e * 2;
    *(__bf16*)(out + off) = (__bf16)W[t];
}

// ---------- CSR build (by dst) ----------
__global__ __launch_bounds__(256) void count_kernel(const int* __restrict__ dst,
                                                    int* __restrict__ counts, int E) {
    int e = blockIdx.x * 256 + threadIdx.x;
    if (e < E) atomicAdd(&counts[dst[e]], 1);
}

__global__ __launch_bounds__(1024) void scan_kernel(const int* __restrict__ counts,
                                                    int* __restrict__ offs, int N) {
    __shared__ int wsum[16], wpre[16];
    const int CH = 20;
    int tid = threadIdx.x, lane = tid & 63, wv = tid >> 6;
    int base = tid * CH;
    int s = 0;
    for (int i = 0; i < CH; i++) { int idx = base + i; s += (idx < N) ? counts[idx] : 0; }
    int run = s;
#pragma unroll
    for (int o = 1; o < 64; o <<= 1) { int v = __shfl_up(run, o, 64); if (lane >= o) run += v; }
    if (lane == 63) wsum[wv] = run;
    __syncthreads();
    if (tid == 0) { int acc = 0; for (int w = 0; w < 16; w++) { wpre[w] = acc; acc += wsum[w]; } }
    __syncthreads();
    int pre = wpre[wv] + (run - s);
    for (int i = 0; i < CH; i++) {
        int idx = base + i;
        if (idx <= N) offs[idx] = pre;
        pre += (idx < N) ? counts[idx] : 0;
    }
}

__global__ __launch_bounds__(256) void bucket_kernel(const int* __restrict__ src,
                                                     const int* __restrict__ dst,
                                                     const int* __restrict__ offs,
                                                     int* __restrict__ cursor,
                                                     int* __restrict__ eids, int E) {
    int e = blockIdx.x * 256 + threadIdx.x;
    if (e >= E) return;
    int d = dst[e];
    int pos = atomicAdd(&cursor[d], 1);
    eids[offs[d] + pos] = src[e];
}

// ---------- y = p0+p1+p2+p3 (bf16 K-quarter partial merge) ----------
__global__ __launch_bounds__(256) void addy4_kernel(const __bf16* __restrict__ p,
                                                    __bf16* __restrict__ y) {
    size_t i = ((size_t)blockIdx.x * 256 + threadIdx.x) * 8;
    bf16x8 a = *(const bf16x8*)(p + i);
    bf16x8 b = *(const bf16x8*)(p + 10240000 + i);
    bf16x8 c = *(const bf16x8*)(p + 20480000 + i);
    bf16x8 d = *(const bf16x8*)(p + 30720000 + i);
    bf16x8 o;
#pragma unroll
    for (int j = 0; j < 8; j++)
        o[j] = (__bf16)(((float)a[j] + (float)b[j]) + ((float)c[j] + (float)d[j]));
    *(bf16x8*)(y + i) = o;
}

// ---------- gather + h1 (y bf16): one wave per node, 16B/lane ----------
__global__ __launch_bounds__(256) void gather_h1_kernel(const __bf16* __restrict__ y,
                                                        const int* __restrict__ offs,
                                                        const int* __restrict__ eids,
                                                        const float* __restrict__ b1,
                                                        __bf16* __restrict__ h1b) {
    const int node = blockIdx.x * 4 + (threadIdx.x >> 6);
    const int c = (threadIdx.x & 63) * 8;
    float s[8];
    bf16x8 v = *(const bf16x8*)(y + (size_t)node * 512 + c);
#pragma unroll
    for (int j = 0; j < 8; j++) s[j] = (float)v[j];
    const int beg = offs[node], end = offs[node + 1];   // wave-uniform
    for (int k = beg; k < end; k++) {
        int sn = eids[k];
        bf16x8 u = *(const bf16x8*)(y + (size_t)sn * 512 + c);
#pragma unroll
        for (int j = 0; j < 8; j++) s[j] += (float)u[j];
    }
    bf16x8 o;
#pragma unroll
    for (int j = 0; j < 8; j++) o[j] = (__bf16)fmaxf(s[j] + b1[c + j], 0.f);
    *(bf16x8*)(h1b + (size_t)node * 512 + c) = o;
}

// =====================================================================
// GEMM1 (barrier-free + explicit B software pipeline):
// Ypart[kh] = X[:, kh*512:+512] @ W1-quarter. 512 thr (8 waves), BM=64,
// all 512 cols; grid (313, 4=kh). A-quarter staged once into 64KB swizzled
// LDS image (ONE barrier). Unroll-by-2 loop: wf loads for tile t+1 issued
// BEFORE tile t's 16 MFMAs (named wfA/wfB sets, static indexing).
// =====================================================================
__global__ __launch_bounds__(512, 4) void gemm1_kernel(const float* __restrict__ X,
                                                       const char* __restrict__ Bpre,
                                                       __bf16* __restrict__ Ybase, int M) {
    extern __shared__ char smem[];   // 65536
    const int tid = threadIdx.x, lane = tid & 63, wv = tid >> 6;
    const int fr = lane & 15, sec = lane >> 4, hi4 = (lane >> 4) * 4;
    const long row0 = (long)blockIdx.x * 64;
    const int kh = blockIdx.y;                         // k-quarter 0..3
    const int cb = wv >> 2, rbase = (wv & 3) * 64;     // wave's col-slab
    const char* Bp = Bpre + ((size_t)cb * 64 + (size_t)kh * 16) * 16384;
    __bf16* Y = Ybase + (size_t)kh * 10240000;

#define LOAD_WF(dst, g) do {                                              \
        const char* bt_ = Bp + (size_t)(g) * 16384;                       \
        _Pragma("unroll") for (int m_ = 0; m_ < 4; m_++)                  \
            dst[m_] = *(const bf16x8*)(bt_ + swz(rbase + m_ * 16 + fr, sec)); \
    } while (0)

    bf16x8 wfA[4], wfB[4];
    LOAD_WF(wfA, 0);   // issue before the barrier: overlaps staging drain

    // ---- stage: 64 rows x 512 k (f32) -> 16 k-tiles x 4KB swizzled image ----
#pragma unroll
    for (int j = 0; j < 8; j++) {
        int b = tid * 16 + j * 8192;
        int tt = b >> 12, bb = b & 4095;
        int row = bb >> 6, soff = bb & 63;
        int s = (soff ^ ((row & 8) << 2)) >> 4;        // inverse swizzle
        long arow = row0 + row; if (arow > (long)M - 1) arow = M - 1;
        const float* p = X + arow * 2048 + kh * 512 + tt * 32 + s * 8;
        float4 a0 = *(const float4*)p;
        float4 a1 = *(const float4*)(p + 4);
        *(bf16x8*)(smem + b) = cvt8(a0, a1);
    }
    __syncthreads();   // the ONLY barrier

    f32x4 acc[4][4];
#pragma unroll
    for (int m = 0; m < 4; m++)
#pragma unroll
        for (int n = 0; n < 4; n++)
#pragma unroll
            for (int r = 0; r < 4; r++) acc[m][n][r] = 0.f;

#define COMPUTE(t, wf) do {                                               \
        const char* at_ = smem + (t) * 4096;                              \
        bf16x8 xf[4];                                                     \
        _Pragma("unroll") for (int n_ = 0; n_ < 4; n_++)                  \
            xf[n_] = *(const bf16x8*)(at_ + swz(n_ * 16 + fr, sec));      \
        _Pragma("unroll") for (int m_ = 0; m_ < 4; m_++)                  \
            _Pragma("unroll") for (int n_ = 0; n_ < 4; n_++)              \
                acc[m_][n_] = __builtin_amdgcn_mfma_f32_16x16x32_bf16(    \
                    wf[m_], xf[n_], acc[m_][n_], 0, 0, 0);                \
    } while (0)

    for (int tt = 0; tt < 16; tt += 2) {
        LOAD_WF(wfB, tt + 1);          // issue next-tile B loads first
        COMPUTE(tt, wfA);
        if (tt + 2 < 16) LOAD_WF(wfA, tt + 2);
        COMPUTE(tt + 1, wfB);
    }
#undef COMPUTE
#undef LOAD_WF

    // epilogue: bf16 partial store (coalesced bf16x4)
#pragma unroll
    for (int n = 0; n < 4; n++) {
        long node = row0 + n * 16 + fr;
        if (node < M) {
#pragma unroll
            for (int m = 0; m < 4; m++) {
                int col = cb * 256 + rbase + m * 16 + hi4;
                *(bf16x4*)(Y + node * 512 + col) = cvt4(acc[m][n]);
            }
        }
    }
}

// =====================================================================
// Fused MLP2+gate, BM=64 (halves weight re-read): 512 thr / 8 waves
// (wm=wv>>2 in {0,1}: 32-row half; wn=wv&3: 128-col quarter).
// Phase 1: h = h1@W2+b2 -> hout f32 + Hs (64KB swizzled bf16 image).
// Phase 2: barrier-free gate from Hs, alpha = rowsum(tanh(.)*Wa).
// LDS 81920B = A dbuf 2x8KB @0 (aS[64] aliases A after phase 1),
//              Hs 16x4KB @16384.  2 blocks/CU exactly.
// =====================================================================
__global__ __launch_bounds__(512) void mlp23_kernel(const __bf16* __restrict__ H1,
                                                    const char* __restrict__ W2p,
                                                    const float* __restrict__ b2,
                                                    const char* __restrict__ Wgp,
                                                    const float* __restrict__ bg,
                                                    const float* __restrict__ Wa,
                                                    float* __restrict__ Hout,
                                                    float* __restrict__ alpha, int M) {
    __shared__ char smem[81920];
    char* Hs = smem + 16384;
    float* aS = (float*)smem;            // aliases A region (dead after phase 1)
    const int tid = threadIdx.x, lane = tid & 63, wv = tid >> 6;
    const int fr = lane & 15, sec = lane >> 4, hi4 = (lane >> 4) * 4;
    const long row0 = (long)blockIdx.x * 64;
    const int wm = wv >> 2, wn = wv & 3;
    const int cbv = wn >> 1, rbase = (wn & 1) * 128;

    // A staging: all 512 thr, LINEAR write at 16*tid; inverse-swizzle source.
    const int b16 = tid * 16;
    const int sh = b16 >> 12;            // 32-k subtile (0/1) within BK=64
    const int bb = b16 & 4095;
    const int srow = bb >> 6;
    const int soff = bb & 63;
    const int ss = (soff ^ ((srow & 8) << 2)) >> 4;
    long arow = row0 + srow; if (arow > (long)M - 1) arow = M - 1;
    const __bf16* ApH = H1 + arow * 512 + sh * 32 + ss * 8;

#define ASEC(b) (smem + (b) * 8192)

    f32x4 acc[8][2];
#pragma unroll
    for (int m = 0; m < 8; m++)
#pragma unroll
        for (int n = 0; n < 2; n++)
#pragma unroll
            for (int r = 0; r < 4; r++) acc[m][n][r] = 0.f;

    {   // prologue: stage k-step 0
        u16x8 v = *(const u16x8*)(ApH);
        *(u16x8*)(ASEC(0) + b16) = v;
    }
    asm volatile("s_waitcnt lgkmcnt(0)" ::: "memory");
    __builtin_amdgcn_s_barrier();

    // ---- phase 1: h = h1 @ W2 (8 steps of BK=64) ----
    int cur = 0;
    for (int tt = 0; tt < 8; tt++) {
        u16x8 av;
        const bool more = (tt + 1 < 8);
        if (more) av = *(const u16x8*)(ApH + (tt + 1) * 64);
#pragma unroll
        for (int h = 0; h < 2; h++) {
            const char* bt = W2p + ((size_t)cbv * 16 + tt * 2 + h) * 16384;
            bf16x8 wf[8], xf[2];
#pragma unroll
            for (int m = 0; m < 8; m++)
                wf[m] = *(const bf16x8*)(bt + swz(rbase + m * 16 + fr, sec));
#pragma unroll
            for (int n = 0; n < 2; n++)
                xf[n] = *(const bf16x8*)(ASEC(cur) + h * 4096 + swz(wm * 32 + n * 16 + fr, sec));
#pragma unroll
            for (int m = 0; m < 8; m++)
#pragma unroll
                for (int n = 0; n < 2; n++)
                    acc[m][n] = __builtin_amdgcn_mfma_f32_16x16x32_bf16(wf[m], xf[n], acc[m][n], 0, 0, 0);
        }
        if (more) {
            const int nxt = cur ^ 1;
            *(u16x8*)(ASEC(nxt) + b16) = av;
            asm volatile("s_waitcnt lgkmcnt(0)" ::: "memory");
            __builtin_amdgcn_s_barrier();
            cur = nxt;
        }
    }

    // phase-1 epilogue: hout f32 + Hs bf16 swizzled image; aS init
#pragma unroll
    for (int n = 0; n < 2; n++) {
        int node = wm * 32 + n * 16 + fr;
        long gnode = row0 + node;
#pragma unroll
        for (int m = 0; m < 8; m++) {
            int hc = wn * 128 + m * 16 + hi4;
            f32x4 bv = *(const f32x4*)(b2 + hc);
            f32x4 v = acc[m][n] + bv;
            if (gnode < M) *(f32x4*)(Hout + gnode * 512 + hc) = v;
            int tt = hc >> 5, sk = (hc & 31) >> 3, e = hc & 7;
            *(bf16x4*)(Hs + tt * 4096 + swz(node, sk) + e * 2) = cvt4(v);
        }
    }
    if (tid < 64) aS[tid] = 0.f;
    asm volatile("s_waitcnt lgkmcnt(0)" ::: "memory");
    __builtin_amdgcn_s_barrier();

    // ---- phase 2: gate (barrier-free; Hs complete) ----
    f32x4 acc2[8][2];
#pragma unroll
    for (int m = 0; m < 8; m++)
#pragma unroll
        for (int n = 0; n < 2; n++)
#pragma unroll
            for (int r = 0; r < 4; r++) acc2[m][n][r] = 0.f;

    for (int g = 0; g < 16; g++) {
        const char* bt = Wgp + ((size_t)cbv * 16 + g) * 16384;
        bf16x8 wf[8], xf[2];
#pragma unroll
        for (int m = 0; m < 8; m++)
            wf[m] = *(const bf16x8*)(bt + swz(rbase + m * 16 + fr, sec));
#pragma unroll
        for (int n = 0; n < 2; n++)
            xf[n] = *(const bf16x8*)(Hs + g * 4096 + swz(wm * 32 + n * 16 + fr, sec));
#pragma unroll
        for (int m = 0; m < 8; m++)
#pragma unroll
            for (int n = 0; n < 2; n++)
                acc2[m][n] = __builtin_amdgcn_mfma_f32_16x16x32_bf16(wf[m], xf[n], acc2[m][n], 0, 0, 0);
    }
#undef ASEC

    // epilogue 2: tanh + Wa dot; reduce over sec (shfl) + wn (LDS atomics)
#pragma unroll
    for (int n = 0; n < 2; n++) {
        float s = 0.f;
#pragma unroll
        for (int m = 0; m < 8; m++) {
            int gc = wn * 128 + m * 16 + hi4;
            f32x4 bgv = *(const f32x4*)(bg + gc);
            f32x4 wav = *(const f32x4*)(Wa + gc);
#pragma unroll
            for (int r = 0; r < 4; r++)
                s += tanhf(acc2[m][n][r] + bgv[r]) * wav[r];
        }
        s += __shfl_xor(s, 16, 64);
        s += __shfl_xor(s, 32, 64);
        if (sec == 0) atomicAdd(&aS[wm * 32 + n * 16 + fr], s);
    }
    __syncthreads();
    if (tid < 64) {
        long node = row0 + tid;
        if (node < M) alpha[node] = aS[tid];
    }
}

// ---------- softmax over 20000 scalars (ba cancels) ----------
__global__ __launch_bounds__(1024) void softmax_kernel(const float* __restrict__ alpha,
                                                       float* __restrict__ att, int N) {
    __shared__ float red[16];
    __shared__ float bc[2];
    int tid = threadIdx.x, lane = tid & 63, wv = tid >> 6;
    float m = -3.4e38f;
    for (int i = tid; i < N; i += 1024) m = fmaxf(m, alpha[i]);
#pragma unroll
    for (int o = 32; o > 0; o >>= 1) m = fmaxf(m, __shfl_xor(m, o, 64));
    if (lane == 0) red[wv] = m;
    __syncthreads();
    if (tid == 0) {
        float mm = red[0];
        for (int i = 1; i < 16; i++) mm = fmaxf(mm, red[i]);
        bc[0] = mm;
    }
    __syncthreads();
    float Mx = bc[0];
    float s = 0.f;
    for (int i = tid; i < N; i += 1024) s += expf(alpha[i] - Mx);
#pragma unroll
    for (int o = 32; o > 0; o >>= 1) s += __shfl_xor(s, o, 64);
    if (lane == 0) red[wv] = s;
    __syncthreads();
    if (tid == 0) {
        float ss = 0.f;
        for (int i = 0; i < 16; i++) ss += red[i];
        bc[1] = ss;
    }
    __syncthreads();
    float inv = 1.f / bc[1];
    for (int i = tid; i < N; i += 1024) att[i] = expf(alpha[i] - Mx) * inv;
}

// ---------- launch ----------
extern "C" void kernel_launch(void* const* d_in, const int* in_sizes, int n_in,
                              void* d_out, int out_size, void* d_ws, size_t ws_size,
                              hipStream_t stream) {
    const float* x  = (const float*)d_in[0];
    const int*   ei = (const int*)d_in[1];     // [2][160000]: src then dst
    const float* W1 = (const float*)d_in[2];
    const float* b1 = (const float*)d_in[3];
    const float* W2 = (const float*)d_in[4];
    const float* b2 = (const float*)d_in[5];
    const float* Wg = (const float*)d_in[6];
    const float* bg = (const float*)d_in[7];
    const float* Wa = (const float*)d_in[8];
    // d_in[9] = ba: cancels in softmax, unused.

    const int M = 20000, IN = 2048, H = 512, E = 160000;

    char* ws = (char*)d_ws;
    __bf16* yp    = (__bf16*)ws;                // 4 partials x 20,480,000 B
    __bf16* ysum  = (__bf16*)(ws + 81920000);   // 20,480,000
    char*  W1p    = ws + 102400000;             //  2,097,152
    char*  W2p    = ws + 104497152;             //    524,288
    char*  Wgp    = ws + 105021440;             //    524,288
    __bf16* h1b   = (__bf16*)(ws + 105545728);  // 20,480,000
    float* alpha  = (float*)(ws + 126025728);   //     80,000
    int*   counts = (int*)(ws + 126105728);     //     80,000
    int*   offs   = (int*)(ws + 126185728);     //     80,004
    int*   cursor = (int*)(ws + 126265732);     //     80,000
    int*   eids   = (int*)(ws + 126345732);     //    640,000

    float* hout = (float*)d_out;                 // [20000][512] f32
    float* att  = hout + (size_t)M * H;          // [20000] f32

    // weights -> pre-tiled + pre-swizzled images (bf16)
    convw_pre_kernel<<<4096, 256, 0, stream>>>(W1, W1p, IN);
    convw_pre_kernel<<<1024, 256, 0, stream>>>(W2, W2p, H);
    convw_pre_kernel<<<1024, 256, 0, stream>>>(Wg, Wgp, H);

    // CSR build by dst
    hipMemsetAsync(counts, 0, M * 4, stream);
    count_kernel<<<(E + 255) / 256, 256, 0, stream>>>(ei + E, counts, E);
    scan_kernel<<<1, 1024, 0, stream>>>(counts, offs, M);
    hipMemsetAsync(cursor, 0, M * 4, stream);
    bucket_kernel<<<(E + 255) / 256, 256, 0, stream>>>(ei, ei + E, offs, cursor, eids, E);

    // y partials = x @ W1 (K-quarter, barrier-free, piped B), then merge
    gemm1_kernel<<<dim3(313, 4), 512, 65536, stream>>>(x, W1p, yp, M);
    addy4_kernel<<<5000, 256, 0, stream>>>(yp, ysum);

    // h1 = bf16(relu(y_self + gather(y) + b1))   (one wave per node)
    gather_h1_kernel<<<5000, 256, 0, stream>>>(ysum, offs, eids, b1, h1b);

    // h = h1@W2+b2 -> d_out, fused alpha = rowsum(tanh(h@Wg+bg)*Wa)
    mlp23_kernel<<<313, 512, 0, stream>>>(h1b, W2p, b2, Wgp, bg, Wa, hout, alpha, M);

    // att = softmax(alpha)
    softmax_kernel<<<1, 1024, 0, stream>>>(alpha, att, M);
}